// Round 5
// baseline (348.267 us; speedup 1.0000x reference)
//
#include <hip/hip_runtime.h>

// Shapes: N=8, C=512, T=8, H=32, W=32, HW=1024, THW=8192, CI=256, CA=128
// All tensor I/O is FLOAT32.
//
// Factorization (phi(audio) constant over h,w):
//   at[n,t,c]   = relu(audio[n,t,:]·alignW[c,:] + alignB[c])          (output 2)
//   phi[n,i,t]  = Wph[i,:]·at[n,t,:] + bph[i]
//   M[n,c,t]    = sum_i Wth[i,c]·phi[n,i,t];  const[n,t] = sum_i bth[i]·phi[n,i,t]
//   Xsum[n,c,t] = sum_hw x[n,c,t,hw]
//   G[n,t,o]    = Wg[o,:]·Xsum[n,:,t] + 1024·bg[o];  GW[n,t,c] = Wz[c,:]·G[n,t,:]
//   f[n,s,t]    = x[n,:,s]·M[n,:,t] + const[n,t]
//   W_y[n,s,c]  = (1/8192)·sum_t f[n,s,t]·GW[n,t,c] + bz[c]
//   BN stats from F[n,t]=sum_s f, S2[n,t1,t2]=sum_s f·f^T (fused into k_fsmall)
//   z = LN_c(0.5·BN(W_y) + 0.5·x)                                    (output 1)

// ---------------- audio -> at -> phi -> M, const ----------------
__global__ __launch_bounds__(256) void k_small1(
    const float* __restrict__ audio, const float* __restrict__ alignW, const float* __restrict__ alignB,
    const float* __restrict__ Wph, const float* __restrict__ bph,
    const float* __restrict__ Wth, const float* __restrict__ bth,
    float* __restrict__ outA, float* __restrict__ constT, float* __restrict__ M)
{
    int b = blockIdx.x; int n = b >> 3; int t = b & 7; int tid = threadIdx.x;
    __shared__ float al[128];
    __shared__ float atl[512];
    __shared__ float phil[256];
    __shared__ float red[256];
    if (tid < 128) al[tid] = audio[(n * 8 + t) * 128 + tid];
    __syncthreads();
    for (int c = tid; c < 512; c += 256) {      // at[n,t,c] (also output 2)
        float acc = alignB[c];
        for (int k = 0; k < 128; ++k) acc += al[k] * alignW[c * 128 + k];
        acc = fmaxf(acc, 0.f);
        atl[c] = acc;
        outA[(n * 8 + t) * 512 + c] = acc;
    }
    __syncthreads();
    {                                           // phi[n,i,t], i = tid
        int i = tid;
        float acc = bph[i];
        for (int c = 0; c < 512; ++c) acc += Wph[i * 512 + c] * atl[c];
        phil[i] = acc;
        red[i] = acc * bth[i];
    }
    __syncthreads();
    for (int sr = 128; sr > 0; sr >>= 1) {      // const[n,t] = sum_i phi*bth
        if (tid < sr) red[tid] += red[tid + sr];
        __syncthreads();
    }
    if (tid == 0) constT[n * 8 + t] = red[0];
    for (int c = tid; c < 512; c += 256) {      // M[n,c,t]
        float acc = 0.f;
        for (int i = 0; i < 256; ++i) acc += Wth[i * 512 + c] * phil[i];
        M[n * 4096 + c * 8 + t] = acc;
    }
}

// ---------------- Xsum: one 64-lane wave per (n,c,t) row of 1024 ----------------
// Runs first: streams all of x once, warming L3 for the later passes.
__global__ __launch_bounds__(64) void k_xsum(const float* __restrict__ x, float* __restrict__ xs)
{
    int b = blockIdx.x; int tid = threadIdx.x;
    const float4* p = reinterpret_cast<const float4*>(x + (size_t)b * 1024);
    float s = 0.f;
    for (int k = 0; k < 4; ++k) {
        float4 v = p[tid + 64 * k];
        s += v.x + v.y + v.z + v.w;
    }
    for (int off = 32; off > 0; off >>= 1) s += __shfl_down(s, off);
    if (tid == 0) xs[b] = s;
}

// ---------------- f[n,s,0..7] + fused F/S2 moments ----------------
// Grid 1024: block b -> n = b>>7, s0 = (b&127)*64 (64 tokens, single t).
// 256 threads = 64 tokens x 4 channel-groups of 128 c. No per-iteration
// cross-lane ops (R4 lesson: 6 shfl/channel serialized the kernel).
__global__ __launch_bounds__(256) void k_fsmall(
    const float* __restrict__ x, const float* __restrict__ M,
    const float* __restrict__ constT, float* __restrict__ fs,
    float* __restrict__ F, float* __restrict__ S2)
{
    int b = blockIdx.x; int n = b >> 7; int s0 = (b & 127) << 6;
    int tid = threadIdx.x; int tok = tid & 63; int cg = tid >> 6;
    const float* Mb = M + n * 4096;
    const float* xb = x + (size_t)n * 4194304 + s0 + tok;
    float p[8] = {0, 0, 0, 0, 0, 0, 0, 0};
    for (int j = 0; j < 128; ++j) {
        int c = cg * 128 + j;
        float xv = xb[(size_t)c * 8192];
        float4 m0 = *reinterpret_cast<const float4*>(Mb + c * 8);
        float4 m1 = *reinterpret_cast<const float4*>(Mb + c * 8 + 4);
        p[0] += xv * m0.x; p[1] += xv * m0.y; p[2] += xv * m0.z; p[3] += xv * m0.w;
        p[4] += xv * m1.x; p[5] += xv * m1.y; p[6] += xv * m1.z; p[7] += xv * m1.w;
    }
    __shared__ float lds[4][64][9];             // pad 8->9: stride 9 banks, conflict-free
    for (int k = 0; k < 8; ++k) lds[cg][tok][k] = p[k];
    __syncthreads();
    if (tid < 64) {                             // one wave finishes 64 tokens
        const float* ct = constT + n * 8;
        float q[8];
        for (int k = 0; k < 8; ++k)
            q[k] = lds[0][tid][k] + lds[1][tid][k] + lds[2][tid][k] + lds[3][tid][k] + ct[k];
        float4* op = reinterpret_cast<float4*>(fs + ((size_t)n * 8192 + s0 + tid) * 8);
        op[0] = make_float4(q[0], q[1], q[2], q[3]);
        op[1] = make_float4(q[4], q[5], q[6], q[7]);
        // moments: 8 first-order + 36 upper-triangle second-order
        float mom[44];
        {
            int idx = 8;
            for (int t1 = 0; t1 < 8; ++t1) {
                mom[t1] = q[t1];
                for (int t2 = t1; t2 < 8; ++t2) { mom[idx] = q[t1] * q[t2]; ++idx; }
            }
        }
        for (int k = 0; k < 44; ++k)            // once per block, not per channel
            for (int off = 32; off > 0; off >>= 1) mom[k] += __shfl_down(mom[k], off);
        if (tid == 0) {
            int idx = 8;
            for (int t1 = 0; t1 < 8; ++t1) {
                atomicAdd(&F[n * 8 + t1], mom[t1]);
                for (int t2 = t1; t2 < 8; ++t2, ++idx) {
                    atomicAdd(&S2[n * 64 + t1 * 8 + t2], mom[idx]);
                    if (t1 != t2) atomicAdd(&S2[n * 64 + t2 * 8 + t1], mom[idx]);
                }
            }
        }
    }
}

// ---------------- G then GW ----------------
__global__ __launch_bounds__(256) void k_small2(
    const float* __restrict__ xs, const float* __restrict__ Wg, const float* __restrict__ bg,
    const float* __restrict__ Wz, float* __restrict__ GW)
{
    int b = blockIdx.x; int n = b >> 3; int t = b & 7; int tid = threadIdx.x;
    __shared__ float xsl[512];
    __shared__ float gl[256];
    for (int c = tid; c < 512; c += 256) xsl[c] = xs[(n * 512 + c) * 8 + t];
    __syncthreads();
    {                                           // G[n,t,o], o = tid
        int o = tid;
        float acc = 1024.f * bg[o];
        for (int c = 0; c < 512; ++c) acc += Wg[o * 512 + c] * xsl[c];
        gl[o] = acc;
    }
    __syncthreads();
    for (int c = tid; c < 512; c += 256) {      // GW[n,t,c]
        float acc = 0.f;
        for (int o = 0; o < 256; ++o) acc += Wz[c * 256 + o] * gl[o];
        GW[(n * 8 + t) * 512 + c] = acc;
    }
}

// ---------------- BN stats (closed form) -> folded tables ----------------
__global__ __launch_bounds__(512) void k_bn(
    const float* __restrict__ F, const float* __restrict__ S2, const float* __restrict__ GW,
    const float* __restrict__ bz, const float* __restrict__ bng, const float* __restrict__ bnb,
    const float* __restrict__ lng, const float* __restrict__ lnb,
    float* __restrict__ pack0, float* __restrict__ gw2)
{
    int n0 = blockIdx.x; int c = threadIdx.x;
    __shared__ float Fl[64];
    __shared__ float S2l[512];
    if (c < 64) Fl[c] = F[c];
    S2l[c] = S2[c];
    __syncthreads();
    const float r = 1.f / 8192.f;
    float meanu = 0.f, e2 = 0.f;
    for (int n = 0; n < 8; ++n) {
        float g[8];
        for (int t = 0; t < 8; ++t) g[t] = GW[(n * 8 + t) * 512 + c];
        for (int t = 0; t < 8; ++t) meanu += Fl[n * 8 + t] * g[t];
        for (int t1 = 0; t1 < 8; ++t1)
            for (int t2 = 0; t2 < 8; ++t2) e2 += S2l[n * 64 + t1 * 8 + t2] * g[t1] * g[t2];
    }
    const float invCnt = 1.f / 65536.f;
    meanu *= r * invCnt;
    e2 *= r * r * invCnt;
    float var = fmaxf(e2 - meanu * meanu, 0.f);
    float bzv = bz[c];
    float mean = meanu + bzv;
    float sc = bng[c] * rsqrtf(var + 1e-5f);
    float sh = bnb[c] - mean * sc;
    if (n0 == 0) {
        float4 pk;
        pk.x = 0.5f * (bzv * sc + sh);   // constant part of 0.5*BN(W_y)
        pk.y = lng[c];
        pk.z = lnb[c];
        pk.w = 0.f;
        *reinterpret_cast<float4*>(pack0 + c * 4) = pk;
    }
    float scale = 0.5f * r * sc;
    for (int t = 0; t < 8; ++t)
        gw2[((size_t)n0 * 512 + c) * 8 + t] = GW[(n0 * 8 + t) * 512 + c] * scale;
}

// ---------------- fused W_y reconstruct + blend + LayerNorm ----------------
// Grid 1024: block b -> n = b>>7, s0 = (b&127)*64 (64 tokens).
// 256 threads = 64 tokens x 4 waves; wave wv covers channels wv*128..wv*128+127.
__global__ __launch_bounds__(256) void k_final(
    const float* __restrict__ x, const float* __restrict__ fs,
    const float* __restrict__ pack0, const float* __restrict__ gw2,
    float* __restrict__ outZ)
{
    int b = blockIdx.x; int n = b >> 7; int s0 = (b & 127) << 6;
    int tid = threadIdx.x; int tok = tid & 63; int wv = tid >> 6;
    __shared__ float redS[2][4][64];
    const float4* fp = reinterpret_cast<const float4*>(fs + ((size_t)n * 8192 + s0 + tok) * 8);
    float4 fdA = fp[0], fdB = fp[1];
    const size_t xbase = (size_t)n * 4194304 + s0 + tok;
    float s1 = 0.f, sq = 0.f;
    for (int j = 0; j < 128; ++j) {
        int c = wv * 128 + j;                    // wave-uniform channel
        const float* gp = gw2 + ((size_t)n * 512 + c) * 8;
        float4 g0 = *reinterpret_cast<const float4*>(gp);
        float4 g1 = *reinterpret_cast<const float4*>(gp + 4);
        float sh2 = pack0[c * 4];
        float xv = x[xbase + (size_t)c * 8192];
        float zp = sh2 + 0.5f * xv
            + fdA.x * g0.x + fdA.y * g0.y + fdA.z * g0.z + fdA.w * g0.w
            + fdB.x * g1.x + fdB.y * g1.y + fdB.z * g1.z + fdB.w * g1.w;
        s1 += zp; sq += zp * zp;
    }
    redS[0][wv][tok] = s1; redS[1][wv][tok] = sq;
    __syncthreads();
    float a = redS[0][0][tok] + redS[0][1][tok] + redS[0][2][tok] + redS[0][3][tok];
    float q = redS[1][0][tok] + redS[1][1][tok] + redS[1][2][tok] + redS[1][3][tok];
    float mean = a * (1.f / 512.f);
    float var = fmaxf(q * (1.f / 512.f) - mean * mean, 0.f);
    float rstd = rsqrtf(var + 1e-5f);
    for (int j = 0; j < 128; ++j) {
        int c = wv * 128 + j;
        const float* gp = gw2 + ((size_t)n * 512 + c) * 8;
        float4 g0 = *reinterpret_cast<const float4*>(gp);
        float4 g1 = *reinterpret_cast<const float4*>(gp + 4);
        float4 pk = *reinterpret_cast<const float4*>(pack0 + c * 4);
        float xv = x[xbase + (size_t)c * 8192];
        float zp = pk.x + 0.5f * xv
            + fdA.x * g0.x + fdA.y * g0.y + fdA.z * g0.z + fdA.w * g0.w
            + fdB.x * g1.x + fdB.y * g1.y + fdB.z * g1.z + fdB.w * g1.w;
        float o = (zp - mean) * rstd * pk.y + pk.z;
        outZ[xbase + (size_t)c * 8192] = o;
    }
}

extern "C" void kernel_launch(void* const* d_in, const int* in_sizes, int n_in,
                              void* d_out, int out_size, void* d_ws, size_t ws_size,
                              hipStream_t stream)
{
    const float* x      = (const float*)d_in[0];
    const float* audio  = (const float*)d_in[1];
    const float* alignW = (const float*)d_in[2];
    const float* alignB = (const float*)d_in[3];
    const float* Wg     = (const float*)d_in[4];
    const float* bg     = (const float*)d_in[5];
    const float* Wth    = (const float*)d_in[6];
    const float* bth    = (const float*)d_in[7];
    const float* Wph    = (const float*)d_in[8];
    const float* bph    = (const float*)d_in[9];
    const float* Wz     = (const float*)d_in[10];
    const float* bz     = (const float*)d_in[11];
    const float* bng    = (const float*)d_in[12];
    const float* bnb    = (const float*)d_in[13];
    const float* lng    = (const float*)d_in[14];
    const float* lnb    = (const float*)d_in[15];
    float* outZ = (float*)d_out;
    float* outA = outZ + 33554432;  // z (N,C,T,H,W) then audio_temp (N,T,C)

    // 256B-aligned workspace; zero the small/accumulated prefix.
    uintptr_t pa = ((uintptr_t)d_ws + 255) & ~(uintptr_t)255;
    float* w = (float*)pa;
    hipMemsetAsync((void*)pa, 0, 133760 * sizeof(float), stream);

    float* constT = w;              // 64
    float* M      = w + 64;         // 32768  [n][c][t]
    float* XS     = w + 32832;      // 32768  [n][c][t]
    float* GW     = w + 65600;      // 32768  [n][t][c]
    float* Fs     = w + 98368;      // 64     (atomic accumulated)
    float* S2     = w + 98432;      // 512    (atomic accumulated)
    float* pack0  = w + 98944;      // 2048   float4 per c: {sh2, ln_g, ln_b, 0}
    float* gw2    = w + 100992;     // 32768  [n][c][t] folded with 0.5*r*bn_scale
    float* fsm    = w + 133760;     // 524288 [n][s][t]

    k_xsum<<<32768, 64, 0, stream>>>(x, XS);       // first: warms L3 with x
    k_small1<<<64, 256, 0, stream>>>(audio, alignW, alignB, Wph, bph, Wth, bth, outA, constT, M);
    k_fsmall<<<1024, 256, 0, stream>>>(x, M, constT, fsm, Fs, S2);
    k_small2<<<64, 256, 0, stream>>>(XS, Wg, bg, Wz, GW);
    k_bn<<<8, 512, 0, stream>>>(Fs, S2, GW, bz, bng, bnb, lng, lnb, pack0, gw2);
    k_final<<<1024, 256, 0, stream>>>(x, fsm, pack0, gw2, outZ);
}

// Round 6
// 254.943 us; speedup vs baseline: 1.3661x; 1.3661x over previous
//
#include <hip/hip_runtime.h>

// Shapes: N=8, C=512, T=8, H=32, W=32, HW=1024, THW=8192, CI=256, CA=128
// All tensor I/O is FLOAT32.
//
// Factorization (phi(audio) constant over h,w):
//   at[n,t,c]   = relu(audio[n,t,:]·alignW[c,:] + alignB[c])          (output 2)
//   phi[n,i,t]  = Wph[i,:]·at[n,t,:] + bph[i]
//   M[n,c,t]    = sum_i Wth[i,c]·phi[n,i,t];  const[n,t] = sum_i bth[i]·phi[n,i,t]
//   Xsum[n,c,t] = sum_hw x[n,c,t,hw]
//   G[n,t,o]    = Wg[o,:]·Xsum[n,:,t] + 1024·bg[o];  GW[n,t,c] = Wz[c,:]·G[n,t,:]
//   f[n,s,t]    = x[n,:,s]·M[n,:,t] + const[n,t]
//   W_y[n,s,c]  = (1/8192)·sum_t f[n,s,t]·GW[n,t,c] + bz[c]
//   BN stats from F[n,t]=sum_s f, S2[n,t1,t2]=sum_s f·f^T (fused into k_fsmall)
//   z = LN_c(0.5·BN(W_y) + 0.5·x)                                    (output 1)

// ---------------- audio -> at -> phi -> M, const ----------------
__global__ __launch_bounds__(256) void k_small1(
    const float* __restrict__ audio, const float* __restrict__ alignW, const float* __restrict__ alignB,
    const float* __restrict__ Wph, const float* __restrict__ bph,
    const float* __restrict__ Wth, const float* __restrict__ bth,
    float* __restrict__ outA, float* __restrict__ constT, float* __restrict__ M)
{
    int b = blockIdx.x; int n = b >> 3; int t = b & 7; int tid = threadIdx.x;
    __shared__ float al[128];
    __shared__ float atl[512];
    __shared__ float phil[256];
    __shared__ float red[256];
    if (tid < 128) al[tid] = audio[(n * 8 + t) * 128 + tid];
    __syncthreads();
    for (int c = tid; c < 512; c += 256) {      // at[n,t,c] (also output 2)
        float a0 = alignB[c], a1 = 0.f, a2 = 0.f, a3 = 0.f;
        const float* Wr = alignW + c * 128;
        #pragma unroll 4
        for (int k = 0; k < 128; k += 4) {      // 4 accumulators: break dep chain
            a0 += al[k] * Wr[k];     a1 += al[k + 1] * Wr[k + 1];
            a2 += al[k + 2] * Wr[k + 2]; a3 += al[k + 3] * Wr[k + 3];
        }
        float acc = fmaxf((a0 + a1) + (a2 + a3), 0.f);
        atl[c] = acc;
        outA[(n * 8 + t) * 512 + c] = acc;
    }
    __syncthreads();
    {                                           // phi[n,i,t], i = tid
        int i = tid;
        float a0 = bph[i], a1 = 0.f, a2 = 0.f, a3 = 0.f;
        const float* Wr = Wph + i * 512;
        #pragma unroll 4
        for (int c = 0; c < 512; c += 4) {
            a0 += Wr[c] * atl[c];         a1 += Wr[c + 1] * atl[c + 1];
            a2 += Wr[c + 2] * atl[c + 2]; a3 += Wr[c + 3] * atl[c + 3];
        }
        float acc = (a0 + a1) + (a2 + a3);
        phil[i] = acc;
        red[i] = acc * bth[i];
    }
    __syncthreads();
    for (int sr = 128; sr > 0; sr >>= 1) {      // const[n,t] = sum_i phi*bth
        if (tid < sr) red[tid] += red[tid + sr];
        __syncthreads();
    }
    if (tid == 0) constT[n * 8 + t] = red[0];
    for (int c = tid; c < 512; c += 256) {      // M[n,c,t]
        float a0 = 0.f, a1 = 0.f, a2 = 0.f, a3 = 0.f;
        #pragma unroll 4
        for (int i = 0; i < 256; i += 4) {
            a0 += Wth[i * 512 + c] * phil[i];
            a1 += Wth[(i + 1) * 512 + c] * phil[i + 1];
            a2 += Wth[(i + 2) * 512 + c] * phil[i + 2];
            a3 += Wth[(i + 3) * 512 + c] * phil[i + 3];
        }
        M[n * 4096 + c * 8 + t] = (a0 + a1) + (a2 + a3);
    }
}

// ---------------- Xsum: one wave per (n,c,t) row of 1024, 4 rows/block ----------------
__global__ __launch_bounds__(256) void k_xsum(const float* __restrict__ x, float* __restrict__ xs)
{
    int row = blockIdx.x * 4 + (threadIdx.x >> 6);
    int lane = threadIdx.x & 63;
    const float4* p = reinterpret_cast<const float4*>(x + (size_t)row * 1024);
    float s = 0.f;
    #pragma unroll
    for (int k = 0; k < 4; ++k) {
        float4 v = p[lane + 64 * k];
        s += v.x + v.y + v.z + v.w;
    }
    for (int off = 32; off > 0; off >>= 1) s += __shfl_down(s, off);
    if (lane == 0) xs[row] = s;
}

// ---------------- f[n,s,0..7] + fused F/S2 moments ----------------
// Grid 1024: block b -> n = b>>7, s0 = (b&127)*64 (64 tokens, single t).
// 256 threads = 64 tokens x 4 channel-groups of 128 c.
// M staged in LDS -> x is the ONLY VMEM stream in the j-loop (R5 lesson:
// per-lane coefficient loads made the loop VMEM-latency-bound).
__global__ __launch_bounds__(256) void k_fsmall(
    const float* __restrict__ x, const float* __restrict__ M,
    const float* __restrict__ constT, float* __restrict__ fs,
    float* __restrict__ F, float* __restrict__ S2)
{
    int b = blockIdx.x; int n = b >> 7; int s0 = (b & 127) << 6;
    int tid = threadIdx.x; int tok = tid & 63; int cg = tid >> 6;
    __shared__ float Ml[512][8];                // 16 KB, M[n] slice
    {
        const float4* src = reinterpret_cast<const float4*>(M + n * 4096);
        float4* dst = reinterpret_cast<float4*>(&Ml[0][0]);
        for (int i = tid; i < 1024; i += 256) dst[i] = src[i];
    }
    __syncthreads();
    const float* xb = x + (size_t)n * 4194304 + s0 + tok;
    float p[8] = {0, 0, 0, 0, 0, 0, 0, 0};
    #pragma unroll 8
    for (int j = 0; j < 128; ++j) {             // 8 x-loads in flight
        int c = cg * 128 + j;
        float xv = xb[(size_t)c * 8192];
        float4 m0 = *reinterpret_cast<const float4*>(&Ml[c][0]);   // uniform -> broadcast
        float4 m1 = *reinterpret_cast<const float4*>(&Ml[c][4]);
        p[0] += xv * m0.x; p[1] += xv * m0.y; p[2] += xv * m0.z; p[3] += xv * m0.w;
        p[4] += xv * m1.x; p[5] += xv * m1.y; p[6] += xv * m1.z; p[7] += xv * m1.w;
    }
    __shared__ float lds[4][64][9];             // pad 8->9: conflict-free
    for (int k = 0; k < 8; ++k) lds[cg][tok][k] = p[k];
    __syncthreads();
    if (tid < 64) {                             // one wave finishes 64 tokens
        const float* ct = constT + n * 8;
        float q[8];
        for (int k = 0; k < 8; ++k)
            q[k] = lds[0][tid][k] + lds[1][tid][k] + lds[2][tid][k] + lds[3][tid][k] + ct[k];
        float4* op = reinterpret_cast<float4*>(fs + ((size_t)n * 8192 + s0 + tid) * 8);
        op[0] = make_float4(q[0], q[1], q[2], q[3]);
        op[1] = make_float4(q[4], q[5], q[6], q[7]);
        float mom[44];                          // 8 first + 36 second moments
        {
            int idx = 8;
            for (int t1 = 0; t1 < 8; ++t1) {
                mom[t1] = q[t1];
                for (int t2 = t1; t2 < 8; ++t2) { mom[idx] = q[t1] * q[t2]; ++idx; }
            }
        }
        for (int k = 0; k < 44; ++k)            // once per block
            for (int off = 32; off > 0; off >>= 1) mom[k] += __shfl_down(mom[k], off);
        if (tid == 0) {
            int idx = 8;
            for (int t1 = 0; t1 < 8; ++t1) {
                atomicAdd(&F[n * 8 + t1], mom[t1]);
                for (int t2 = t1; t2 < 8; ++t2, ++idx) {
                    atomicAdd(&S2[n * 64 + t1 * 8 + t2], mom[idx]);
                    if (t1 != t2) atomicAdd(&S2[n * 64 + t2 * 8 + t1], mom[idx]);
                }
            }
        }
    }
}

// ---------------- G then GW ----------------
__global__ __launch_bounds__(256) void k_small2(
    const float* __restrict__ xs, const float* __restrict__ Wg, const float* __restrict__ bg,
    const float* __restrict__ Wz, float* __restrict__ GW)
{
    int b = blockIdx.x; int n = b >> 3; int t = b & 7; int tid = threadIdx.x;
    __shared__ float xsl[512];
    __shared__ float gl[256];
    for (int c = tid; c < 512; c += 256) xsl[c] = xs[(n * 512 + c) * 8 + t];
    __syncthreads();
    {                                           // G[n,t,o], o = tid
        int o = tid;
        float a0 = 1024.f * bg[o], a1 = 0.f, a2 = 0.f, a3 = 0.f;
        const float* Wr = Wg + o * 512;
        #pragma unroll 4
        for (int c = 0; c < 512; c += 4) {
            a0 += Wr[c] * xsl[c];         a1 += Wr[c + 1] * xsl[c + 1];
            a2 += Wr[c + 2] * xsl[c + 2]; a3 += Wr[c + 3] * xsl[c + 3];
        }
        gl[o] = (a0 + a1) + (a2 + a3);
    }
    __syncthreads();
    for (int c = tid; c < 512; c += 256) {      // GW[n,t,c]
        float a0 = 0.f, a1 = 0.f, a2 = 0.f, a3 = 0.f;
        const float* Wr = Wz + c * 256;
        #pragma unroll 4
        for (int o = 0; o < 256; o += 4) {
            a0 += Wr[o] * gl[o];         a1 += Wr[o + 1] * gl[o + 1];
            a2 += Wr[o + 2] * gl[o + 2]; a3 += Wr[o + 3] * gl[o + 3];
        }
        GW[(n * 8 + t) * 512 + c] = (a0 + a1) + (a2 + a3);
    }
}

// ---------------- BN stats (closed form) -> folded tables ----------------
__global__ __launch_bounds__(512) void k_bn(
    const float* __restrict__ F, const float* __restrict__ S2, const float* __restrict__ GW,
    const float* __restrict__ bz, const float* __restrict__ bng, const float* __restrict__ bnb,
    const float* __restrict__ lng, const float* __restrict__ lnb,
    float* __restrict__ pack0, float* __restrict__ gw2)
{
    int n0 = blockIdx.x; int c = threadIdx.x;
    __shared__ float Fl[64];
    __shared__ float S2l[512];
    if (c < 64) Fl[c] = F[c];
    S2l[c] = S2[c];
    __syncthreads();
    const float r = 1.f / 8192.f;
    float meanu = 0.f, e2 = 0.f;
    for (int n = 0; n < 8; ++n) {
        float g[8];
        for (int t = 0; t < 8; ++t) g[t] = GW[(n * 8 + t) * 512 + c];
        for (int t = 0; t < 8; ++t) meanu += Fl[n * 8 + t] * g[t];
        for (int t1 = 0; t1 < 8; ++t1)
            for (int t2 = 0; t2 < 8; ++t2) e2 += S2l[n * 64 + t1 * 8 + t2] * g[t1] * g[t2];
    }
    const float invCnt = 1.f / 65536.f;
    meanu *= r * invCnt;
    e2 *= r * r * invCnt;
    float var = fmaxf(e2 - meanu * meanu, 0.f);
    float bzv = bz[c];
    float mean = meanu + bzv;
    float sc = bng[c] * rsqrtf(var + 1e-5f);
    float sh = bnb[c] - mean * sc;
    if (n0 == 0) {
        float4 pk;
        pk.x = 0.5f * (bzv * sc + sh);   // constant part of 0.5*BN(W_y)
        pk.y = lng[c];
        pk.z = lnb[c];
        pk.w = 0.f;
        *reinterpret_cast<float4*>(pack0 + c * 4) = pk;
    }
    float scale = 0.5f * r * sc;
    for (int t = 0; t < 8; ++t)
        gw2[((size_t)n0 * 512 + c) * 8 + t] = GW[(n0 * 8 + t) * 512 + c] * scale;
}

// ---------------- fused W_y reconstruct + blend + LayerNorm ----------------
// Grid 1024: block b -> n = b>>7, s0 = (b&127)*64. 256 threads = 64 tokens x
// 4 waves; wave wv covers channels wv*128..+127. gw2/pack0 staged in LDS ->
// x is the only VMEM stream in the j-loops.
__global__ __launch_bounds__(256) void k_final(
    const float* __restrict__ x, const float* __restrict__ fs,
    const float* __restrict__ pack0, const float* __restrict__ gw2,
    float* __restrict__ outZ)
{
    int b = blockIdx.x; int n = b >> 7; int s0 = (b & 127) << 6;
    int tid = threadIdx.x; int tok = tid & 63; int wv = tid >> 6;
    __shared__ float GWl[512][8];               // 16 KB gw2[n] slice
    __shared__ float4 PKl[512];                 // 8 KB {sh2, lng, lnb, 0}
    __shared__ float redS[2][4][64];
    {
        const float4* src = reinterpret_cast<const float4*>(gw2 + (size_t)n * 4096);
        float4* dst = reinterpret_cast<float4*>(&GWl[0][0]);
        for (int i = tid; i < 1024; i += 256) dst[i] = src[i];
        const float4* ps = reinterpret_cast<const float4*>(pack0);
        for (int i = tid; i < 512; i += 256) PKl[i] = ps[i];
    }
    __syncthreads();
    const float4* fp = reinterpret_cast<const float4*>(fs + ((size_t)n * 8192 + s0 + tok) * 8);
    float4 fdA = fp[0], fdB = fp[1];
    const size_t xbase = (size_t)n * 4194304 + s0 + tok;
    float s1 = 0.f, sq = 0.f;
    #pragma unroll 8
    for (int j = 0; j < 128; ++j) {
        int c = wv * 128 + j;
        float4 g0 = *reinterpret_cast<const float4*>(&GWl[c][0]);
        float4 g1 = *reinterpret_cast<const float4*>(&GWl[c][4]);
        float xv = x[xbase + (size_t)c * 8192];
        float zp = PKl[c].x + 0.5f * xv
            + fdA.x * g0.x + fdA.y * g0.y + fdA.z * g0.z + fdA.w * g0.w
            + fdB.x * g1.x + fdB.y * g1.y + fdB.z * g1.z + fdB.w * g1.w;
        s1 += zp; sq += zp * zp;
    }
    redS[0][wv][tok] = s1; redS[1][wv][tok] = sq;
    __syncthreads();
    float a = redS[0][0][tok] + redS[0][1][tok] + redS[0][2][tok] + redS[0][3][tok];
    float q = redS[1][0][tok] + redS[1][1][tok] + redS[1][2][tok] + redS[1][3][tok];
    float mean = a * (1.f / 512.f);
    float var = fmaxf(q * (1.f / 512.f) - mean * mean, 0.f);
    float rstd = rsqrtf(var + 1e-5f);
    #pragma unroll 8
    for (int j = 0; j < 128; ++j) {
        int c = wv * 128 + j;
        float4 g0 = *reinterpret_cast<const float4*>(&GWl[c][0]);
        float4 g1 = *reinterpret_cast<const float4*>(&GWl[c][4]);
        float4 pk = PKl[c];
        float xv = x[xbase + (size_t)c * 8192];
        float zp = pk.x + 0.5f * xv
            + fdA.x * g0.x + fdA.y * g0.y + fdA.z * g0.z + fdA.w * g0.w
            + fdB.x * g1.x + fdB.y * g1.y + fdB.z * g1.z + fdB.w * g1.w;
        float o = (zp - mean) * rstd * pk.y + pk.z;
        outZ[xbase + (size_t)c * 8192] = o;
    }
}

extern "C" void kernel_launch(void* const* d_in, const int* in_sizes, int n_in,
                              void* d_out, int out_size, void* d_ws, size_t ws_size,
                              hipStream_t stream)
{
    const float* x      = (const float*)d_in[0];
    const float* audio  = (const float*)d_in[1];
    const float* alignW = (const float*)d_in[2];
    const float* alignB = (const float*)d_in[3];
    const float* Wg     = (const float*)d_in[4];
    const float* bg     = (const float*)d_in[5];
    const float* Wth    = (const float*)d_in[6];
    const float* bth    = (const float*)d_in[7];
    const float* Wph    = (const float*)d_in[8];
    const float* bph    = (const float*)d_in[9];
    const float* Wz     = (const float*)d_in[10];
    const float* bz     = (const float*)d_in[11];
    const float* bng    = (const float*)d_in[12];
    const float* bnb    = (const float*)d_in[13];
    const float* lng    = (const float*)d_in[14];
    const float* lnb    = (const float*)d_in[15];
    float* outZ = (float*)d_out;
    float* outA = outZ + 33554432;  // z (N,C,T,H,W) then audio_temp (N,T,C)

    uintptr_t pa = ((uintptr_t)d_ws + 255) & ~(uintptr_t)255;
    float* w = (float*)pa;

    float* constT = w;              // 64
    float* M      = w + 64;         // 32768  [n][c][t]
    float* XS     = w + 32832;      // 32768  [n][c][t]
    float* GW     = w + 65600;      // 32768  [n][t][c]
    float* Fs     = w + 98368;      // 64     (atomic accumulated)
    float* S2     = w + 98432;      // 512    (atomic accumulated)
    float* pack0  = w + 98944;      // 2048   float4 per c: {sh2, ln_g, ln_b, 0}
    float* gw2    = w + 100992;     // 32768  [n][c][t] folded with 0.5*r*bn_scale
    float* fsm    = w + 133760;     // 524288 [n][s][t]

    // only the atomically-accumulated buffers need zeroing
    hipMemsetAsync((void*)Fs, 0, 576 * sizeof(float), stream);

    k_xsum<<<8192, 256, 0, stream>>>(x, XS);       // first: warms L3 with x
    k_small1<<<64, 256, 0, stream>>>(audio, alignW, alignB, Wph, bph, Wth, bth, outA, constT, M);
    k_fsmall<<<1024, 256, 0, stream>>>(x, M, constT, fsm, Fs, S2);
    k_small2<<<64, 256, 0, stream>>>(XS, Wg, bg, Wz, GW);
    k_bn<<<8, 512, 0, stream>>>(Fs, S2, GW, bz, bng, bnb, lng, lnb, pack0, gw2);
    k_final<<<1024, 256, 0, stream>>>(x, fsm, pack0, gw2, outZ);
}

// Round 7
// 197.691 us; speedup vs baseline: 1.7617x; 1.2896x over previous
//
#include <hip/hip_runtime.h>

// Shapes: N=8, C=512, T=8, H=32, W=32, HW=1024, THW=8192, CI=256, CA=128
// All tensor I/O is FLOAT32.
//
// Factorization (phi(audio) constant over h,w):
//   at[n,t,c]   = relu(audio[n,t,:]·alignW[c,:] + alignB[c])          (output 2)
//   phi[n,i,t]  = Wph[i,:]·at[n,t,:] + bph[i]
//   M[n,c,t]    = sum_i Wth[i,c]·phi[n,i,t];  const[n,t] = sum_i bth[i]·phi[n,i,t]
//   Xsum[n,c,t] = sum_hw x[n,c,t,hw]
//   G[n,t,o]    = Wg[o,:]·Xsum[n,:,t] + 1024·bg[o];  GW[n,t,c] = Wz[c,:]·G[n,t,:]
//   f[n,s,t]    = x[n,:,s]·M[n,:,t] + const[n,t]
//   W_y[n,s,c]  = (1/8192)·sum_t f[n,s,t]·GW[n,t,c] + bz[c]
//   BN stats from per-block moment partials Part[b][44] (no atomics, no memset)
//   z = LN_c(0.5·BN(W_y) + 0.5·x)                                    (output 1)

// ---------------- audio -> at -> phi -> M, const ----------------
__global__ __launch_bounds__(256) void k_small1(
    const float* __restrict__ audio, const float* __restrict__ alignW, const float* __restrict__ alignB,
    const float* __restrict__ Wph, const float* __restrict__ bph,
    const float* __restrict__ Wth, const float* __restrict__ bth,
    float* __restrict__ outA, float* __restrict__ constT, float* __restrict__ M)
{
    int b = blockIdx.x; int n = b >> 3; int t = b & 7; int tid = threadIdx.x;
    __shared__ float al[128];
    __shared__ float atl[512];
    __shared__ float phil[256];
    __shared__ float red[256];
    if (tid < 128) al[tid] = audio[(n * 8 + t) * 128 + tid];
    __syncthreads();
    for (int c = tid; c < 512; c += 256) {      // at[n,t,c] (also output 2)
        float a0 = alignB[c], a1 = 0.f, a2 = 0.f, a3 = 0.f;
        const float* Wr = alignW + c * 128;
        #pragma unroll 4
        for (int k = 0; k < 128; k += 4) {
            a0 += al[k] * Wr[k];         a1 += al[k + 1] * Wr[k + 1];
            a2 += al[k + 2] * Wr[k + 2]; a3 += al[k + 3] * Wr[k + 3];
        }
        float acc = fmaxf((a0 + a1) + (a2 + a3), 0.f);
        atl[c] = acc;
        outA[(n * 8 + t) * 512 + c] = acc;
    }
    __syncthreads();
    {                                           // phi[n,i,t], i = tid
        int i = tid;
        float a0 = bph[i], a1 = 0.f, a2 = 0.f, a3 = 0.f;
        const float* Wr = Wph + i * 512;
        #pragma unroll 4
        for (int c = 0; c < 512; c += 4) {
            a0 += Wr[c] * atl[c];         a1 += Wr[c + 1] * atl[c + 1];
            a2 += Wr[c + 2] * atl[c + 2]; a3 += Wr[c + 3] * atl[c + 3];
        }
        float acc = (a0 + a1) + (a2 + a3);
        phil[i] = acc;
        red[i] = acc * bth[i];
    }
    __syncthreads();
    for (int sr = 128; sr > 0; sr >>= 1) {      // const[n,t] = sum_i phi*bth
        if (tid < sr) red[tid] += red[tid + sr];
        __syncthreads();
    }
    if (tid == 0) constT[n * 8 + t] = red[0];
    for (int c = tid; c < 512; c += 256) {      // M[n,c,t]
        float a0 = 0.f, a1 = 0.f, a2 = 0.f, a3 = 0.f;
        #pragma unroll 4
        for (int i = 0; i < 256; i += 4) {
            a0 += Wth[i * 512 + c] * phil[i];
            a1 += Wth[(i + 1) * 512 + c] * phil[i + 1];
            a2 += Wth[(i + 2) * 512 + c] * phil[i + 2];
            a3 += Wth[(i + 3) * 512 + c] * phil[i + 3];
        }
        M[n * 4096 + c * 8 + t] = (a0 + a1) + (a2 + a3);
    }
}

// ---------------- Xsum: one wave per (n,c,t) row of 1024, 4 rows/block ----------------
__global__ __launch_bounds__(256) void k_xsum(const float* __restrict__ x, float* __restrict__ xs)
{
    int row = blockIdx.x * 4 + (threadIdx.x >> 6);
    int lane = threadIdx.x & 63;
    const float4* p = reinterpret_cast<const float4*>(x + (size_t)row * 1024);
    float s = 0.f;
    #pragma unroll
    for (int k = 0; k < 4; ++k) {
        float4 v = p[lane + 64 * k];
        s += v.x + v.y + v.z + v.w;
    }
    for (int off = 32; off > 0; off >>= 1) s += __shfl_down(s, off);
    if (lane == 0) xs[row] = s;
}

// ---------------- f[n,s,0..7] + per-block F/S2 moment partials ----------------
// Grid 512: block b -> n = b>>6, s0 = (b&63)*128 (128 tokens, single t).
// 256 threads = 4 waves (one channel-group of 128 c each); each lane owns
// 2 tokens via float2 loads (R6 lesson: 1-dword loads left BW idle).
__global__ __launch_bounds__(256) void k_fsmall(
    const float* __restrict__ x, const float* __restrict__ M,
    const float* __restrict__ constT, float* __restrict__ fs,
    float* __restrict__ Part)
{
    int b = blockIdx.x; int n = b >> 6; int s0 = (b & 63) << 7;
    int tid = threadIdx.x; int lane = tid & 63; int cg = tid >> 6;
    __shared__ float Ml[512][8];                // 16 KB, M[n] slice
    {
        const float4* src = reinterpret_cast<const float4*>(M + n * 4096);
        float4* dst = reinterpret_cast<float4*>(&Ml[0][0]);
        for (int i = tid; i < 1024; i += 256) dst[i] = src[i];
    }
    __syncthreads();
    const float* xb = x + (size_t)n * 4194304 + s0 + lane * 2;
    float2 p2[8];
    #pragma unroll
    for (int k = 0; k < 8; ++k) p2[k] = make_float2(0.f, 0.f);
    #pragma unroll 8
    for (int j = 0; j < 128; ++j) {
        int c = cg * 128 + j;
        float2 xv = *reinterpret_cast<const float2*>(xb + (size_t)c * 8192);
        float4 m0 = *reinterpret_cast<const float4*>(&Ml[c][0]);   // uniform -> broadcast
        float4 m1 = *reinterpret_cast<const float4*>(&Ml[c][4]);
        p2[0].x += xv.x * m0.x; p2[0].y += xv.y * m0.x;
        p2[1].x += xv.x * m0.y; p2[1].y += xv.y * m0.y;
        p2[2].x += xv.x * m0.z; p2[2].y += xv.y * m0.z;
        p2[3].x += xv.x * m0.w; p2[3].y += xv.y * m0.w;
        p2[4].x += xv.x * m1.x; p2[4].y += xv.y * m1.x;
        p2[5].x += xv.x * m1.y; p2[5].y += xv.y * m1.y;
        p2[6].x += xv.x * m1.z; p2[6].y += xv.y * m1.z;
        p2[7].x += xv.x * m1.w; p2[7].y += xv.y * m1.w;
    }
    __shared__ float ldsT[4][8][130];           // [cg][t][tok] float2 writes, conflict-free
    #pragma unroll
    for (int k = 0; k < 8; ++k)
        *reinterpret_cast<float2*>(&ldsT[cg][k][lane * 2]) = p2[k];
    __syncthreads();
    __shared__ float partm[2][44];
    if (tid < 128) {                            // token tok = tid
        int tok = tid; int wv = tid >> 6;
        const float* ct = constT + n * 8;
        float q[8];
        #pragma unroll
        for (int k = 0; k < 8; ++k)
            q[k] = ldsT[0][k][tok] + ldsT[1][k][tok] + ldsT[2][k][tok] + ldsT[3][k][tok] + ct[k];
        float4* op = reinterpret_cast<float4*>(fs + ((size_t)n * 8192 + s0 + tok) * 8);
        op[0] = make_float4(q[0], q[1], q[2], q[3]);
        op[1] = make_float4(q[4], q[5], q[6], q[7]);
        float mom[44];
        {
            int idx = 8;
            for (int t1 = 0; t1 < 8; ++t1) {
                mom[t1] = q[t1];
                for (int t2 = t1; t2 < 8; ++t2) { mom[idx] = q[t1] * q[t2]; ++idx; }
            }
        }
        for (int k = 0; k < 44; ++k)
            for (int off = 32; off > 0; off >>= 1) mom[k] += __shfl_down(mom[k], off);
        if ((tid & 63) == 0)
            for (int k = 0; k < 44; ++k) partm[wv][k] = mom[k];
    }
    __syncthreads();
    if (tid < 44) Part[b * 44 + tid] = partm[0][tid] + partm[1][tid];
}

// ---------------- G then GW ----------------
__global__ __launch_bounds__(256) void k_small2(
    const float* __restrict__ xs, const float* __restrict__ Wg, const float* __restrict__ bg,
    const float* __restrict__ Wz, float* __restrict__ GW)
{
    int b = blockIdx.x; int n = b >> 3; int t = b & 7; int tid = threadIdx.x;
    __shared__ float xsl[512];
    __shared__ float gl[256];
    for (int c = tid; c < 512; c += 256) xsl[c] = xs[(n * 512 + c) * 8 + t];
    __syncthreads();
    {                                           // G[n,t,o], o = tid
        int o = tid;
        float a0 = 1024.f * bg[o], a1 = 0.f, a2 = 0.f, a3 = 0.f;
        const float* Wr = Wg + o * 512;
        #pragma unroll 4
        for (int c = 0; c < 512; c += 4) {
            a0 += Wr[c] * xsl[c];         a1 += Wr[c + 1] * xsl[c + 1];
            a2 += Wr[c + 2] * xsl[c + 2]; a3 += Wr[c + 3] * xsl[c + 3];
        }
        gl[o] = (a0 + a1) + (a2 + a3);
    }
    __syncthreads();
    for (int c = tid; c < 512; c += 256) {      // GW[n,t,c]
        float a0 = 0.f, a1 = 0.f, a2 = 0.f, a3 = 0.f;
        const float* Wr = Wz + c * 256;
        #pragma unroll 4
        for (int o = 0; o < 256; o += 4) {
            a0 += Wr[o] * gl[o];         a1 += Wr[o + 1] * gl[o + 1];
            a2 += Wr[o + 2] * gl[o + 2]; a3 += Wr[o + 3] * gl[o + 3];
        }
        GW[(n * 8 + t) * 512 + c] = (a0 + a1) + (a2 + a3);
    }
}

// ---------------- reduce Part -> BN stats -> folded tables ----------------
__global__ __launch_bounds__(512) void k_bn(
    const float* __restrict__ Part, const float* __restrict__ GW,
    const float* __restrict__ bz, const float* __restrict__ bng, const float* __restrict__ bnb,
    const float* __restrict__ lng, const float* __restrict__ lnb,
    float* __restrict__ pack0, float* __restrict__ gw2)
{
    int n0 = blockIdx.x; int c = threadIdx.x;
    __shared__ float Fl[64];
    __shared__ float S2l[512];
    if (c < 352) {                              // 8 n x 44 moments; 64 fsmall blocks per n
        int n = c / 44, k = c % 44;
        float v = 0.f;
        for (int i = 0; i < 64; ++i) v += Part[(n * 64 + i) * 44 + k];
        if (k < 8) Fl[n * 8 + k] = v;
        else {
            int kk = k - 8; int t1 = 0;
            while (kk >= 8 - t1) { kk -= 8 - t1; ++t1; }
            int t2 = t1 + kk;
            S2l[n * 64 + t1 * 8 + t2] = v;
            S2l[n * 64 + t2 * 8 + t1] = v;
        }
    }
    __syncthreads();
    const float r = 1.f / 8192.f;
    float meanu = 0.f, e2 = 0.f;
    for (int n = 0; n < 8; ++n) {
        float g[8];
        for (int t = 0; t < 8; ++t) g[t] = GW[(n * 8 + t) * 512 + c];
        for (int t = 0; t < 8; ++t) meanu += Fl[n * 8 + t] * g[t];
        for (int t1 = 0; t1 < 8; ++t1)
            for (int t2 = 0; t2 < 8; ++t2) e2 += S2l[n * 64 + t1 * 8 + t2] * g[t1] * g[t2];
    }
    const float invCnt = 1.f / 65536.f;
    meanu *= r * invCnt;
    e2 *= r * r * invCnt;
    float var = fmaxf(e2 - meanu * meanu, 0.f);
    float bzv = bz[c];
    float mean = meanu + bzv;
    float sc = bng[c] * rsqrtf(var + 1e-5f);
    float sh = bnb[c] - mean * sc;
    if (n0 == 0) {
        float4 pk;
        pk.x = 0.5f * (bzv * sc + sh);   // constant part of 0.5*BN(W_y)
        pk.y = lng[c];
        pk.z = lnb[c];
        pk.w = 0.f;
        *reinterpret_cast<float4*>(pack0 + c * 4) = pk;
    }
    float scale = 0.5f * r * sc;
    for (int t = 0; t < 8; ++t)
        gw2[((size_t)n0 * 512 + c) * 8 + t] = GW[(n0 * 8 + t) * 512 + c] * scale;
}

// ---------------- fused W_y reconstruct + blend + LayerNorm ----------------
// Grid 512: block b -> n = b>>6, s0 = (b&63)*128. 4 waves; wave cg covers
// channels cg*128..+127; each lane owns 2 tokens via float2.
__global__ __launch_bounds__(256) void k_final(
    const float* __restrict__ x, const float* __restrict__ fs,
    const float* __restrict__ pack0, const float* __restrict__ gw2,
    float* __restrict__ outZ)
{
    int b = blockIdx.x; int n = b >> 6; int s0 = (b & 63) << 7;
    int tid = threadIdx.x; int lane = tid & 63; int cg = tid >> 6;
    __shared__ float GWl[512][8];               // 16 KB gw2[n] slice
    __shared__ float4 PKl[512];                 // 8 KB {sh2, lng, lnb, 0}
    __shared__ float redS[2][4][128];           // 4 KB
    {
        const float4* src = reinterpret_cast<const float4*>(gw2 + (size_t)n * 4096);
        float4* dst = reinterpret_cast<float4*>(&GWl[0][0]);
        for (int i = tid; i < 1024; i += 256) dst[i] = src[i];
        const float4* ps = reinterpret_cast<const float4*>(pack0);
        for (int i = tid; i < 512; i += 256) PKl[i] = ps[i];
    }
    __syncthreads();
    float4 fA0, fB0, fA1, fB1;                  // f rows for the 2 tokens
    {
        const float4* fp = reinterpret_cast<const float4*>(fs + ((size_t)n * 8192 + s0 + lane * 2) * 8);
        fA0 = fp[0]; fB0 = fp[1]; fA1 = fp[2]; fB1 = fp[3];
    }
    const size_t xbase = (size_t)n * 4194304 + s0 + lane * 2;
    float2 s1 = make_float2(0.f, 0.f), sq = make_float2(0.f, 0.f);
    #pragma unroll 4
    for (int j = 0; j < 128; ++j) {
        int c = cg * 128 + j;
        float2 xv = *reinterpret_cast<const float2*>(&x[xbase + (size_t)c * 8192]);
        float4 g0 = *reinterpret_cast<const float4*>(&GWl[c][0]);
        float4 g1 = *reinterpret_cast<const float4*>(&GWl[c][4]);
        float pk0 = PKl[c].x;
        float z0 = pk0 + 0.5f * xv.x
            + fA0.x * g0.x + fA0.y * g0.y + fA0.z * g0.z + fA0.w * g0.w
            + fB0.x * g1.x + fB0.y * g1.y + fB0.z * g1.z + fB0.w * g1.w;
        float z1 = pk0 + 0.5f * xv.y
            + fA1.x * g0.x + fA1.y * g0.y + fA1.z * g0.z + fA1.w * g0.w
            + fB1.x * g1.x + fB1.y * g1.y + fB1.z * g1.z + fB1.w * g1.w;
        s1.x += z0; sq.x += z0 * z0;
        s1.y += z1; sq.y += z1 * z1;
    }
    *reinterpret_cast<float2*>(&redS[0][cg][lane * 2]) = s1;
    *reinterpret_cast<float2*>(&redS[1][cg][lane * 2]) = sq;
    __syncthreads();
    float mean0, rstd0, mean1, rstd1;
    {
        int t0 = lane * 2, t1 = lane * 2 + 1;
        float a0 = redS[0][0][t0] + redS[0][1][t0] + redS[0][2][t0] + redS[0][3][t0];
        float q0 = redS[1][0][t0] + redS[1][1][t0] + redS[1][2][t0] + redS[1][3][t0];
        float a1 = redS[0][0][t1] + redS[0][1][t1] + redS[0][2][t1] + redS[0][3][t1];
        float q1 = redS[1][0][t1] + redS[1][1][t1] + redS[1][2][t1] + redS[1][3][t1];
        mean0 = a0 * (1.f / 512.f);
        rstd0 = rsqrtf(fmaxf(q0 * (1.f / 512.f) - mean0 * mean0, 0.f) + 1e-5f);
        mean1 = a1 * (1.f / 512.f);
        rstd1 = rsqrtf(fmaxf(q1 * (1.f / 512.f) - mean1 * mean1, 0.f) + 1e-5f);
    }
    #pragma unroll 4
    for (int j = 0; j < 128; ++j) {
        int c = cg * 128 + j;
        float2 xv = *reinterpret_cast<const float2*>(&x[xbase + (size_t)c * 8192]);
        float4 g0 = *reinterpret_cast<const float4*>(&GWl[c][0]);
        float4 g1 = *reinterpret_cast<const float4*>(&GWl[c][4]);
        float4 pk = PKl[c];
        float z0 = pk.x + 0.5f * xv.x
            + fA0.x * g0.x + fA0.y * g0.y + fA0.z * g0.z + fA0.w * g0.w
            + fB0.x * g1.x + fB0.y * g1.y + fB0.z * g1.z + fB0.w * g1.w;
        float z1 = pk.x + 0.5f * xv.y
            + fA1.x * g0.x + fA1.y * g0.y + fA1.z * g0.z + fA1.w * g0.w
            + fB1.x * g1.x + fB1.y * g1.y + fB1.z * g1.z + fB1.w * g1.w;
        float2 o;
        o.x = (z0 - mean0) * rstd0 * pk.y + pk.z;
        o.y = (z1 - mean1) * rstd1 * pk.y + pk.z;
        *reinterpret_cast<float2*>(&outZ[xbase + (size_t)c * 8192]) = o;
    }
}

extern "C" void kernel_launch(void* const* d_in, const int* in_sizes, int n_in,
                              void* d_out, int out_size, void* d_ws, size_t ws_size,
                              hipStream_t stream)
{
    const float* x      = (const float*)d_in[0];
    const float* audio  = (const float*)d_in[1];
    const float* alignW = (const float*)d_in[2];
    const float* alignB = (const float*)d_in[3];
    const float* Wg     = (const float*)d_in[4];
    const float* bg     = (const float*)d_in[5];
    const float* Wth    = (const float*)d_in[6];
    const float* bth    = (const float*)d_in[7];
    const float* Wph    = (const float*)d_in[8];
    const float* bph    = (const float*)d_in[9];
    const float* Wz     = (const float*)d_in[10];
    const float* bz     = (const float*)d_in[11];
    const float* bng    = (const float*)d_in[12];
    const float* bnb    = (const float*)d_in[13];
    const float* lng    = (const float*)d_in[14];
    const float* lnb    = (const float*)d_in[15];
    float* outZ = (float*)d_out;
    float* outA = outZ + 33554432;  // z (N,C,T,H,W) then audio_temp (N,T,C)

    uintptr_t pa = ((uintptr_t)d_ws + 255) & ~(uintptr_t)255;
    float* w = (float*)pa;

    float* constT = w;              // 64
    float* M      = w + 64;         // 32768  [n][c][t]
    float* XS     = w + 32832;      // 32768  [n][c][t]
    float* GW     = w + 65600;      // 32768  [n][t][c]
    float* Part   = w + 98368;      // 22528  [512 blocks][44] moment partials
    float* pack0  = w + 120896;     // 2048   float4 per c: {sh2, ln_g, ln_b, 0}
    float* gw2    = w + 122944;     // 32768  [n][c][t] folded with 0.5*r*bn_scale
    float* fsm    = w + 155712;     // 524288 [n][s][t]
    // every buffer fully written before read each call -> no memset needed
    // (R6 lesson: a 2 KB hipMemsetAsync node cost 77 us/replay in the graph)

    k_xsum<<<8192, 256, 0, stream>>>(x, XS);       // first: warms L3 with x
    k_small1<<<64, 256, 0, stream>>>(audio, alignW, alignB, Wph, bph, Wth, bth, outA, constT, M);
    k_fsmall<<<512, 256, 0, stream>>>(x, M, constT, fsm, Part);
    k_small2<<<64, 256, 0, stream>>>(XS, Wg, bg, Wz, GW);
    k_bn<<<8, 512, 0, stream>>>(Part, GW, bz, bng, bnb, lng, lnb, pack0, gw2);
    k_final<<<512, 256, 0, stream>>>(x, fsm, pack0, gw2, outZ);
}